// Round 8
// baseline (5720.378 us; speedup 1.0000x reference)
//
#include <hip/hip_runtime.h>
#include <cstdint>
#include <cstddef>

#define SEQ 256
#define BATCH 128
#define HID 1024
#define H3 3072
#define TCH 32                 // timesteps per chunk
#define NCH (SEQ/TCH)          // chunks per layer
#define CROWS (TCH*BATCH)      // 4096 rows per chunk GEMM

typedef __bf16 bf16x8 __attribute__((ext_vector_type(8)));
typedef float f32x4 __attribute__((ext_vector_type(4)));
typedef unsigned short ushort8 __attribute__((ext_vector_type(8)));
typedef unsigned long long u64x2 __attribute__((ext_vector_type(2)));

static __device__ __forceinline__ unsigned short f2bf(float f){
  unsigned int u = __float_as_uint(f);
  u += 0x7fffu + ((u >> 16) & 1u);
  return (unsigned short)(u >> 16);
}
static __device__ __forceinline__ float sigm(float x){
  return 1.0f / (1.0f + __expf(-x));
}
static __device__ __forceinline__ float tanh_(float x){
  x = fminf(15.0f, fmaxf(-15.0f, x));
  float e = __expf(2.0f * x);
  return (e - 1.0f) / (e + 1.0f);
}

// ---------------- prologue kernels ----------------

__global__ __launch_bounds__(256) void cvt_bf16(const float* __restrict__ in,
                                                unsigned short* __restrict__ out, int n4){
  int i = blockIdx.x * blockDim.x + threadIdx.x;
  int stride = gridDim.x * blockDim.x;
  for (; i < n4; i += stride){
    float4 v = reinterpret_cast<const float4*>(in)[i];
    ushort4 o = { f2bf(v.x), f2bf(v.y), f2bf(v.z), f2bf(v.w) };
    reinterpret_cast<ushort4*>(out)[i] = o;
  }
}

__global__ __launch_bounds__(256) void embed_gather(const int* __restrict__ src,
                                                    const float* __restrict__ embW,
                                                    unsigned short* __restrict__ x0){
  int bx = blockIdx.x;            // = s*BATCH + b
  int s = bx >> 7, b = bx & 127;
  int row = src[b * SEQ + s];
  float4 v = reinterpret_cast<const float4*>(embW + (size_t)row * HID)[threadIdx.x];
  ushort4 o = { f2bf(v.x), f2bf(v.y), f2bf(v.z), f2bf(v.w) };
  reinterpret_cast<ushort4*>(x0 + (size_t)bx * HID)[threadIdx.x] = o;
}

__global__ __launch_bounds__(256) void zero_u32(unsigned* __restrict__ p, int n){
  int i = blockIdx.x * blockDim.x + threadIdx.x;
  if (i < n) p[i] = 0u;
}

// ---------------- chunk GEMM: gi = A @ B^T, C stored COLUMN-major ----------------
#define BM 128
#define BN 128
#define BK 32
#define LDT 40

__global__ __launch_bounds__(256) void gemm_xw(
    const unsigned short* __restrict__ A,
    const unsigned short* __restrict__ B,
    float* __restrict__ C)
{
  __shared__ unsigned short As[2][BM][LDT];
  __shared__ unsigned short Bs[2][BN][LDT];
  int tid = threadIdx.x;
  int lane = tid & 63, wid = tid >> 6;
  int fr = lane & 15, kg = lane >> 4;
  int wr = wid >> 1, wc = wid & 1;
  int brow = blockIdx.x * BM;
  int bcol = blockIdx.y * BN;

  int r0 = tid >> 2;
  int r1 = 64 + (tid >> 2);
  int k8 = (tid & 3) * 8;

  const unsigned short* Ab = A + (size_t)brow * HID;
  const unsigned short* Bb = B + (size_t)bcol * HID;

  f32x4 acc[4][4] = {};
  ushort8 a0, a1, b0, b1;

  a0 = *(const ushort8*)(Ab + (size_t)r0 * HID + k8);
  a1 = *(const ushort8*)(Ab + (size_t)r1 * HID + k8);
  b0 = *(const ushort8*)(Bb + (size_t)r0 * HID + k8);
  b1 = *(const ushort8*)(Bb + (size_t)r1 * HID + k8);
  *(ushort8*)&As[0][r0][k8] = a0;
  *(ushort8*)&As[0][r1][k8] = a1;
  *(ushort8*)&Bs[0][r0][k8] = b0;
  *(ushort8*)&Bs[0][r1][k8] = b1;
  __syncthreads();

  for (int kt = 0; kt < HID / BK; ++kt){
    int cur = kt & 1;
    if (kt < HID / BK - 1){
      int ko = (kt + 1) * BK + k8;
      a0 = *(const ushort8*)(Ab + (size_t)r0 * HID + ko);
      a1 = *(const ushort8*)(Ab + (size_t)r1 * HID + ko);
      b0 = *(const ushort8*)(Bb + (size_t)r0 * HID + ko);
      b1 = *(const ushort8*)(Bb + (size_t)r1 * HID + ko);
    }
    bf16x8 af[4], bfr[4];
    #pragma unroll
    for (int m = 0; m < 4; ++m)
      af[m] = *(const bf16x8*)&As[cur][wr*64 + m*16 + fr][kg*8];
    #pragma unroll
    for (int n = 0; n < 4; ++n)
      bfr[n] = *(const bf16x8*)&Bs[cur][wc*64 + n*16 + fr][kg*8];
    #pragma unroll
    for (int m = 0; m < 4; ++m)
      #pragma unroll
      for (int n = 0; n < 4; ++n)
        acc[m][n] = __builtin_amdgcn_mfma_f32_16x16x32_bf16(af[m], bfr[n], acc[m][n], 0,0,0);
    if (kt < HID / BK - 1){
      int nxt = cur ^ 1;
      *(ushort8*)&As[nxt][r0][k8] = a0;
      *(ushort8*)&As[nxt][r1][k8] = a1;
      *(ushort8*)&Bs[nxt][r0][k8] = b0;
      *(ushort8*)&Bs[nxt][r1][k8] = b1;
      __syncthreads();
    }
  }

  #pragma unroll
  for (int m = 0; m < 4; ++m){
    int rowb = brow + wr*64 + m*16 + kg*4;
    #pragma unroll
    for (int n = 0; n < 4; ++n){
      int col = bcol + wc*64 + n*16 + fr;
      *(f32x4*)(C + (size_t)col * CROWS + rowb) = acc[m][n];
    }
  }
}

// ---------------- persistent GRU chunk kernel ----------------
// grid 256 WGs x 256 thr (4 waves), 1 WG/CU. blockIdx.x = rg*64 + ct.
// WG tile: 32 batch rows (rg) x 16 hidden cols (ct) x 3 gates.
// Waves K-split 1024 into 4x256; partials via padded f32 LDS; epilogue
// thread = (1 row, 2 cols), rows wave-aligned (wave w owns rows 8w..8w+7).
// Sync: PER-PRODUCER flags (no RMW): producer wave does vmcnt(0) then one
// relaxed store to flags[s][rg][w][ct]; consumer wave polls 256 words with
// 4 coalesced 64-lane loads + __all. Next step's poll subsumes intra-WG
// sync after the reduction barrier, so only ONE barrier per step.

__global__ __launch_bounds__(256) void gru_persist(
    const unsigned short* __restrict__ Whh,   // layer [3072][1024] bf16
    const float* __restrict__ bih,
    const float* __restrict__ bhh,
    const float* __restrict__ gi,             // [3072][CROWS] col-major chunk
    float* __restrict__ ys_out,               // layer1: d_out ys base; else null
    unsigned short* __restrict__ x_next,      // layer0: x1 chunk base; else null
    unsigned long long* hbA,                  // bf16 h ping-pong (u64 granules)
    unsigned long long* hbB,
    float* __restrict__ hf32,                 // per-thread f32 h carry
    float* __restrict__ state_out,            // layer state slot
    int t0,
    unsigned* __restrict__ flags)             // [TCH][4rg][4w][64ct]
{
  __shared__ unsigned short Wlds[48 * 1024];  // 96 KB, fragment-order
  __shared__ float redF[96 * 65];             // 24.4 KB padded partials

  int tid = threadIdx.x;
  int lane = tid & 63, w = tid >> 6;
  int ct = blockIdx.x & 63, rg = blockIdx.x >> 6;
  int c0 = ct * 16;
  int R0g = rg * 32;
  int fr = lane & 15, kg = lane >> 4;

  // ---- stage weights in fragment order (once per launch) ----
  #pragma unroll
  for (int j = 0; j < 24; ++j){
    int cid = j * 256 + tid;                  // 0..6143
    int rr = cid & 15;                        // W-row (= col) within tile
    int sl = (cid >> 4) & 127;                // 16B k-slot
    int g  = cid >> 11;                       // gate
    int ks = sl >> 2, kgs = sl & 3;
    int ldso = ((g * 32 + ks) * 64 + kgs * 16 + rr) * 8;
    int grow = g * HID + c0 + rr;
    *(ushort8*)&Wlds[ldso] = *(const ushort8*)(Whh + (size_t)grow * HID + sl * 8);
  }

  // ---- epilogue cell assignment: thread = (row, 2 cols), wave-aligned rows ----
  int row = tid >> 3, cp = tid & 7;           // row 0..31 (= w*8 + lane>>3)
  int rt_ = row >> 4, r16 = row & 15, q = r16 & 3;
  int lbase = (r16 >> 2) * 16 + cp * 2;       // MFMA C lane for colA
  int colA = c0 + cp * 2, colB = colA + 1;
  int grow_ = R0g + row;                      // global batch row

  float brA = bih[colA] + bhh[colA];
  float bzA = bih[HID + colA] + bhh[HID + colA];
  float biA = bih[2*HID + colA];
  float bhA = bhh[2*HID + colA];
  float brB = bih[colB] + bhh[colB];
  float bzB = bih[HID + colB] + bhh[HID + colB];
  float biB = bih[2*HID + colB];
  float bhB = bhh[2*HID + colB];

  float* hfp = hf32 + ((size_t)blockIdx.x * 256 + tid) * 2;
  float hprev0 = 0.0f, hprev1 = 0.0f;
  if (t0 > 0){ hprev0 = hfp[0]; hprev1 = hfp[1]; }

  const unsigned short* wbase = Wlds + lane * 8;
  const size_t GOFF = (size_t)HID * CROWS;
  const float* giA = gi + (size_t)colA * CROWS + R0g + row;
  const float* giB = gi + (size_t)colB * CROWS + R0g + row;

  __syncthreads();   // weights staged

  // gi for s = 0
  float grA = giA[0], gzA = giA[GOFF], gnA = giA[2*GOFF];
  float grB = giB[0], gzB = giB[GOFF], gnB = giB[2*GOFF];

  for (int s = 0; s < TCH; ++s){
    int t = t0 + s;

    // per-wave poll of the 256 producer flags of this rowgroup (coalesced)
    if (s > 0){
      const unsigned* fp = flags + (size_t)((s - 1) * 4 + rg) * 256;
      int lim = 4000000;
      for (;;){
        unsigned f0 = __hip_atomic_load(fp +       lane, __ATOMIC_RELAXED, __HIP_MEMORY_SCOPE_AGENT);
        unsigned f1 = __hip_atomic_load(fp +  64 + lane, __ATOMIC_RELAXED, __HIP_MEMORY_SCOPE_AGENT);
        unsigned f2 = __hip_atomic_load(fp + 128 + lane, __ATOMIC_RELAXED, __HIP_MEMORY_SCOPE_AGENT);
        unsigned f3 = __hip_atomic_load(fp + 192 + lane, __ATOMIC_RELAXED, __HIP_MEMORY_SCOPE_AGENT);
        if (__all((f0 & f1 & f2 & f3) != 0) || !--lim) break;
        __builtin_amdgcn_s_sleep(1);
      }
      asm volatile("" ::: "memory");   // no hoisting h-loads above the poll
    }

    f32x4 acc[2][3] = {};
    if (t > 0){
      const unsigned long long* hin = (t & 1) ? hbB : hbA;
      // wave K-slice: k = w*256 .. +255; A-frag row = R0g + rt*16 + fr
      size_t abase = ((size_t)(R0g + fr)) * 256 + (w << 6) + (kg << 1);
      bf16x8 a[2][8];
      #pragma unroll
      for (int rt = 0; rt < 2; ++rt){
        #pragma unroll
        for (int j = 0; j < 8; ++j){
          size_t o = abase + (size_t)rt * 4096 + j * 8;
          u64x2 uu;
          uu[0] = __hip_atomic_load(hin + o,     __ATOMIC_RELAXED, __HIP_MEMORY_SCOPE_AGENT);
          uu[1] = __hip_atomic_load(hin + o + 1, __ATOMIC_RELAXED, __HIP_MEMORY_SCOPE_AGENT);
          a[rt][j] = __builtin_bit_cast(bf16x8, uu);
        }
      }
      #pragma unroll
      for (int j = 0; j < 8; ++j){
        int ks = (w << 3) + j;
        bf16x8 b0 = *(const bf16x8*)(wbase + (size_t)(     ks) * 512);
        bf16x8 b1 = *(const bf16x8*)(wbase + (size_t)(32 + ks) * 512);
        bf16x8 b2 = *(const bf16x8*)(wbase + (size_t)(64 + ks) * 512);
        acc[0][0] = __builtin_amdgcn_mfma_f32_16x16x32_bf16(a[0][j], b0, acc[0][0], 0,0,0);
        acc[0][1] = __builtin_amdgcn_mfma_f32_16x16x32_bf16(a[0][j], b1, acc[0][1], 0,0,0);
        acc[0][2] = __builtin_amdgcn_mfma_f32_16x16x32_bf16(a[0][j], b2, acc[0][2], 0,0,0);
        acc[1][0] = __builtin_amdgcn_mfma_f32_16x16x32_bf16(a[1][j], b0, acc[1][0], 0,0,0);
        acc[1][1] = __builtin_amdgcn_mfma_f32_16x16x32_bf16(a[1][j], b1, acc[1][1], 0,0,0);
        acc[1][2] = __builtin_amdgcn_mfma_f32_16x16x32_bf16(a[1][j], b2, acc[1][2], 0,0,0);
      }
    }

    // partials -> LDS (padded)
    #pragma unroll
    for (int rt = 0; rt < 2; ++rt)
      #pragma unroll
      for (int g = 0; g < 3; ++g)
        #pragma unroll
        for (int qq = 0; qq < 4; ++qq)
          redF[(((w * 6 + rt * 3 + g) * 4 + qq) * 65) + lane] = acc[rt][g][qq];
    __syncthreads();   // the ONE barrier per step

    // epilogue: sum 4 waves' partials for my (row, 2 cols)
    float v0[3], v1[3];
    #pragma unroll
    for (int g = 0; g < 3; ++g){
      int fo = ((rt_ * 3 + g) * 4 + q) * 65 + lbase;
      float s0 = 0.f, s1 = 0.f;
      #pragma unroll
      for (int ww = 0; ww < 4; ++ww){
        s0 += redF[ww * 1560 + fo];
        s1 += redF[ww * 1560 + fo + 1];
      }
      v0[g] = s0; v1[g] = s1;
    }

    float rA = sigm(grA + v0[0] + brA);
    float zA = sigm(gzA + v0[1] + bzA);
    float nA = tanh_(gnA + biA + rA * (v0[2] + bhA));
    float h0 = (1.0f - zA) * nA + zA * hprev0;
    float rB = sigm(grB + v1[0] + brB);
    float zB = sigm(gzB + v1[1] + bzB);
    float nB = tanh_(gnB + biB + rB * (v1[2] + bhB));
    float h1 = (1.0f - zB) * nB + zB * hprev1;
    hprev0 = h0; hprev1 = h1;

    // publish h (one u32 per thread), per-wave drain, per-wave flag store
    unsigned long long* hout = (t & 1) ? hbA : hbB;
    unsigned hu = (unsigned)f2bf(h0) | ((unsigned)f2bf(h1) << 16);
    __hip_atomic_store((unsigned*)hout + (((size_t)grow_ * HID + colA) >> 1), hu,
                       __ATOMIC_RELAXED, __HIP_MEMORY_SCOPE_AGENT);
    asm volatile("s_waitcnt vmcnt(0)" ::: "memory");
    if (lane == 0 && s < TCH - 1)
      __hip_atomic_store(flags + (size_t)((s * 4 + rg) * 4 + w) * 64 + ct, 1u,
                         __ATOMIC_RELAXED, __HIP_MEMORY_SCOPE_AGENT);

    // bulk outputs OFF the critical path
    if (ys_out){
      float2 yv = { h0, h1 };
      *(float2*)&ys_out[((size_t)t * BATCH + grow_) * HID + colA] = yv;
    }
    if (x_next)
      *(unsigned*)&x_next[((size_t)s * BATCH + grow_) * HID + colA] = hu;
    if (t == SEQ - 1){
      float2 sv = { h0, h1 };
      *(float2*)&state_out[(size_t)grow_ * HID + colA] = sv;
    }
    if (s == TCH - 1){ hfp[0] = hprev0; hfp[1] = hprev1; }

    // prefetch next step's gi
    if (s + 1 < TCH){
      const float* gA = giA + (size_t)(s + 1) * BATCH;
      const float* gB = giB + (size_t)(s + 1) * BATCH;
      grA = gA[0]; gzA = gA[GOFF]; gnA = gA[2*GOFF];
      grB = gB[0]; gzB = gB[GOFF]; gnB = gB[2*GOFF];
    }
  }
}

// ---------------- launch ----------------

extern "C" void kernel_launch(void* const* d_in, const int* in_sizes, int n_in,
                              void* d_out, int out_size, void* d_ws, size_t ws_size,
                              hipStream_t stream){
  (void)in_sizes; (void)n_in; (void)out_size; (void)ws_size;
  const int*   src  = (const int*)  d_in[0];
  const float* embW = (const float*)d_in[1];
  const float* Wih  = (const float*)d_in[2];
  const float* Whh  = (const float*)d_in[3];
  const float* bih  = (const float*)d_in[4];
  const float* bhh  = (const float*)d_in[5];
  float* out = (float*)d_out;

  char* ws = (char*)d_ws;
  size_t off = 0;
  auto carve = [&](size_t bytes) -> void* {
    void* p = ws + off;
    off += (bytes + 255) & ~(size_t)255;
    return p;
  };
  const size_t WELEM = (size_t)2 * H3 * HID;
  const int NFLAG = 2 * NCH * TCH * 4 * 4 * 64;  // u32 flags, all launches (2 MB)
  unsigned short* wihb = (unsigned short*)carve(WELEM * 2);
  unsigned short* whhb = (unsigned short*)carve(WELEM * 2);
  unsigned short* x0   = (unsigned short*)carve((size_t)SEQ*BATCH*HID*2);
  unsigned short* x1   = (unsigned short*)carve((size_t)SEQ*BATCH*HID*2);
  float*          gi   = (float*)         carve((size_t)CROWS*H3*4);
  unsigned long long* hbA = (unsigned long long*)carve((size_t)BATCH*HID*2);
  unsigned long long* hbB = (unsigned long long*)carve((size_t)BATCH*HID*2);
  float*          hf32 = (float*)         carve((size_t)256*256*2*4);
  unsigned*       flags= (unsigned*)      carve((size_t)NFLAG * 4);

  cvt_bf16<<<2048, 256, 0, stream>>>(Wih, wihb, (int)(WELEM/4));
  cvt_bf16<<<2048, 256, 0, stream>>>(Whh, whhb, (int)(WELEM/4));
  embed_gather<<<SEQ*BATCH, 256, 0, stream>>>(src, embW, x0);
  zero_u32<<<(NFLAG + 255)/256, 256, 0, stream>>>(flags, NFLAG);

  float* state = out + (size_t)SEQ*BATCH*HID;
  for (int l = 0; l < 2; ++l){
    const float* bihl = bih + l*H3;
    const float* bhhl = bhh + l*H3;
    const unsigned short* wl = wihb + (size_t)l*H3*HID;
    const unsigned short* vl = whhb + (size_t)l*H3*HID;
    for (int cch = 0; cch < NCH; ++cch){
      const unsigned short* Achunk = (l == 0) ? (x0 + (size_t)cch*CROWS*HID)
                                              : (x1 + (size_t)cch*CROWS*HID);
      gemm_xw<<<dim3(CROWS/BM, H3/BN), 256, 0, stream>>>(Achunk, wl, gi);
      int launch_id = l*NCH + cch;
      gru_persist<<<256, 256, 0, stream>>>(
          vl, bihl, bhhl, gi,
          (l == 1) ? out : nullptr,
          (l == 0) ? (x1 + (size_t)cch*CROWS*HID) : nullptr,
          hbA, hbB, hf32,
          state + (size_t)l*BATCH*HID,
          cch*TCH,
          flags + (size_t)launch_id * TCH * 4 * 4 * 64);
    }
  }
}

// Round 9
// 3841.388 us; speedup vs baseline: 1.4891x; 1.4891x over previous
//
#include <hip/hip_runtime.h>
#include <cstdint>
#include <cstddef>

#define SEQ 256
#define BATCH 128
#define HID 1024
#define H3 3072
#define TCH 32                 // timesteps per chunk
#define NCH (SEQ/TCH)          // chunks per layer
#define CROWS (TCH*BATCH)      // 4096 rows per chunk GEMM

typedef __bf16 bf16x8 __attribute__((ext_vector_type(8)));
typedef float f32x4 __attribute__((ext_vector_type(4)));
typedef unsigned short ushort8 __attribute__((ext_vector_type(8)));
typedef unsigned long long u64x2 __attribute__((ext_vector_type(2)));

static __device__ __forceinline__ unsigned short f2bf(float f){
  unsigned int u = __float_as_uint(f);
  u += 0x7fffu + ((u >> 16) & 1u);
  return (unsigned short)(u >> 16);
}
static __device__ __forceinline__ float sigm(float x){
  return 1.0f / (1.0f + __expf(-x));
}
static __device__ __forceinline__ float tanh_(float x){
  x = fminf(15.0f, fmaxf(-15.0f, x));
  float e = __expf(2.0f * x);
  return (e - 1.0f) / (e + 1.0f);
}

// ---------------- prologue kernels ----------------

__global__ __launch_bounds__(256) void cvt_bf16(const float* __restrict__ in,
                                                unsigned short* __restrict__ out, int n4){
  int i = blockIdx.x * blockDim.x + threadIdx.x;
  int stride = gridDim.x * blockDim.x;
  for (; i < n4; i += stride){
    float4 v = reinterpret_cast<const float4*>(in)[i];
    ushort4 o = { f2bf(v.x), f2bf(v.y), f2bf(v.z), f2bf(v.w) };
    reinterpret_cast<ushort4*>(out)[i] = o;
  }
}

__global__ __launch_bounds__(256) void embed_gather(const int* __restrict__ src,
                                                    const float* __restrict__ embW,
                                                    unsigned short* __restrict__ x0){
  int bx = blockIdx.x;            // = s*BATCH + b
  int s = bx >> 7, b = bx & 127;
  int row = src[b * SEQ + s];
  float4 v = reinterpret_cast<const float4*>(embW + (size_t)row * HID)[threadIdx.x];
  ushort4 o = { f2bf(v.x), f2bf(v.y), f2bf(v.z), f2bf(v.w) };
  reinterpret_cast<ushort4*>(x0 + (size_t)bx * HID)[threadIdx.x] = o;
}

__global__ __launch_bounds__(256) void zero_u32(unsigned* __restrict__ p, int n){
  int i = blockIdx.x * blockDim.x + threadIdx.x;
  if (i < n) p[i] = 0u;
}

// ---------------- chunk GEMM: gi = A @ B^T, C stored COLUMN-major ----------------
#define BM 128
#define BN 128
#define BK 32
#define LDT 40

__global__ __launch_bounds__(256) void gemm_xw(
    const unsigned short* __restrict__ A,
    const unsigned short* __restrict__ B,
    float* __restrict__ C)
{
  __shared__ unsigned short As[2][BM][LDT];
  __shared__ unsigned short Bs[2][BN][LDT];
  int tid = threadIdx.x;
  int lane = tid & 63, wid = tid >> 6;
  int fr = lane & 15, kg = lane >> 4;
  int wr = wid >> 1, wc = wid & 1;
  int brow = blockIdx.x * BM;
  int bcol = blockIdx.y * BN;

  int r0 = tid >> 2;
  int r1 = 64 + (tid >> 2);
  int k8 = (tid & 3) * 8;

  const unsigned short* Ab = A + (size_t)brow * HID;
  const unsigned short* Bb = B + (size_t)bcol * HID;

  f32x4 acc[4][4] = {};
  ushort8 a0, a1, b0, b1;

  a0 = *(const ushort8*)(Ab + (size_t)r0 * HID + k8);
  a1 = *(const ushort8*)(Ab + (size_t)r1 * HID + k8);
  b0 = *(const ushort8*)(Bb + (size_t)r0 * HID + k8);
  b1 = *(const ushort8*)(Bb + (size_t)r1 * HID + k8);
  *(ushort8*)&As[0][r0][k8] = a0;
  *(ushort8*)&As[0][r1][k8] = a1;
  *(ushort8*)&Bs[0][r0][k8] = b0;
  *(ushort8*)&Bs[0][r1][k8] = b1;
  __syncthreads();

  for (int kt = 0; kt < HID / BK; ++kt){
    int cur = kt & 1;
    if (kt < HID / BK - 1){
      int ko = (kt + 1) * BK + k8;
      a0 = *(const ushort8*)(Ab + (size_t)r0 * HID + ko);
      a1 = *(const ushort8*)(Ab + (size_t)r1 * HID + ko);
      b0 = *(const ushort8*)(Bb + (size_t)r0 * HID + ko);
      b1 = *(const ushort8*)(Bb + (size_t)r1 * HID + ko);
    }
    bf16x8 af[4], bfr[4];
    #pragma unroll
    for (int m = 0; m < 4; ++m)
      af[m] = *(const bf16x8*)&As[cur][wr*64 + m*16 + fr][kg*8];
    #pragma unroll
    for (int n = 0; n < 4; ++n)
      bfr[n] = *(const bf16x8*)&Bs[cur][wc*64 + n*16 + fr][kg*8];
    #pragma unroll
    for (int m = 0; m < 4; ++m)
      #pragma unroll
      for (int n = 0; n < 4; ++n)
        acc[m][n] = __builtin_amdgcn_mfma_f32_16x16x32_bf16(af[m], bfr[n], acc[m][n], 0,0,0);
    if (kt < HID / BK - 1){
      int nxt = cur ^ 1;
      *(ushort8*)&As[nxt][r0][k8] = a0;
      *(ushort8*)&As[nxt][r1][k8] = a1;
      *(ushort8*)&Bs[nxt][r0][k8] = b0;
      *(ushort8*)&Bs[nxt][r1][k8] = b1;
      __syncthreads();
    }
  }

  #pragma unroll
  for (int m = 0; m < 4; ++m){
    int rowb = brow + wr*64 + m*16 + kg*4;
    #pragma unroll
    for (int n = 0; n < 4; ++n){
      int col = bcol + wc*64 + n*16 + fr;
      *(f32x4*)(C + (size_t)col * CROWS + rowb) = acc[m][n];
    }
  }
}

// ---------------- persistent GRU chunk kernel ----------------
// grid 256 WGs x 256 thr (4 waves), 1 WG/CU. blockIdx.x = rg*64 + ct.
// WG tile: 32 batch rows (rg) x 16 hidden cols (ct) x 3 gates.
// Waves K-split 1024 into 4x256; partials via padded f32 LDS.
// Sync (thin-poll, no RMW): producer WG -> barrier(vmcnt drain) -> tid0
// plain flag store to flags[s][rg][ct]; consumer: WAVE 0 ONLY polls the 64
// words with one coalesced 64-lane load + __all, then __syncthreads releases.
// Bulk outputs (ys/x_next/state) AFTER the flag.

__global__ __launch_bounds__(256) void gru_persist(
    const unsigned short* __restrict__ Whh,   // layer [3072][1024] bf16
    const float* __restrict__ bih,
    const float* __restrict__ bhh,
    const float* __restrict__ gi,             // [3072][CROWS] col-major chunk
    float* __restrict__ ys_out,               // layer1: d_out ys base; else null
    unsigned short* __restrict__ x_next,      // layer0: x1 chunk base; else null
    unsigned long long* hbA,                  // bf16 h ping-pong (u64 granules)
    unsigned long long* hbB,
    float* __restrict__ hf32,                 // per-thread f32 h carry
    float* __restrict__ state_out,            // layer state slot
    int t0,
    unsigned* __restrict__ flags)             // [TCH][4rg][64ct]
{
  __shared__ unsigned short Wlds[48 * 1024];  // 96 KB, fragment-order
  __shared__ float redF[96 * 65];             // 24.4 KB padded partials

  int tid = threadIdx.x;
  int lane = tid & 63, w = tid >> 6;
  int ct = blockIdx.x & 63, rg = blockIdx.x >> 6;
  int c0 = ct * 16;
  int R0g = rg * 32;
  int fr = lane & 15, kg = lane >> 4;

  // ---- stage weights in fragment order (once per launch) ----
  #pragma unroll
  for (int j = 0; j < 24; ++j){
    int cid = j * 256 + tid;                  // 0..6143
    int rr = cid & 15;                        // W-row (= col) within tile
    int sl = (cid >> 4) & 127;                // 16B k-slot
    int g  = cid >> 11;                       // gate
    int ks = sl >> 2, kgs = sl & 3;
    int ldso = ((g * 32 + ks) * 64 + kgs * 16 + rr) * 8;
    int grow = g * HID + c0 + rr;
    *(ushort8*)&Wlds[ldso] = *(const ushort8*)(Whh + (size_t)grow * HID + sl * 8);
  }

  // ---- epilogue cell assignment: thread = (row, 2 cols) ----
  int row = tid >> 3, cp = tid & 7;           // row 0..31, colpair 0..7
  int rt_ = row >> 4, r16 = row & 15, q = r16 & 3;
  int lbase = (r16 >> 2) * 16 + cp * 2;       // MFMA C lane for colA
  int colA = c0 + cp * 2, colB = colA + 1;
  int grow_ = R0g + row;                      // global batch row

  float brA = bih[colA] + bhh[colA];
  float bzA = bih[HID + colA] + bhh[HID + colA];
  float biA = bih[2*HID + colA];
  float bhA = bhh[2*HID + colA];
  float brB = bih[colB] + bhh[colB];
  float bzB = bih[HID + colB] + bhh[HID + colB];
  float biB = bih[2*HID + colB];
  float bhB = bhh[2*HID + colB];

  float* hfp = hf32 + ((size_t)blockIdx.x * 256 + tid) * 2;
  float hprev0 = 0.0f, hprev1 = 0.0f;
  if (t0 > 0){ hprev0 = hfp[0]; hprev1 = hfp[1]; }

  const unsigned short* wbase = Wlds + lane * 8;
  const size_t GOFF = (size_t)HID * CROWS;
  const float* giA = gi + (size_t)colA * CROWS + R0g + row;
  const float* giB = gi + (size_t)colB * CROWS + R0g + row;

  __syncthreads();   // weights staged

  // gi for s = 0
  float grA = giA[0], gzA = giA[GOFF], gnA = giA[2*GOFF];
  float grB = giB[0], gzB = giB[GOFF], gnB = giB[2*GOFF];

  for (int s = 0; s < TCH; ++s){
    int t = t0 + s;

    // thin poll: wave 0 only, one coalesced 64-word load over the rg's flags
    if (s > 0){
      if (w == 0){
        const unsigned* fp = flags + (size_t)((s - 1) * 4 + rg) * 64;
        int lim = 4000000;
        for (;;){
          unsigned f = __hip_atomic_load(fp + lane, __ATOMIC_RELAXED, __HIP_MEMORY_SCOPE_AGENT);
          if (__all(f != 0) || !--lim) break;
          __builtin_amdgcn_s_sleep(1);
        }
      }
      __syncthreads();                 // release all waves
      asm volatile("" ::: "memory");   // no hoisting h-loads above the poll
    }

    f32x4 acc[2][3] = {};
    if (t > 0){
      const unsigned long long* hin = (t & 1) ? hbB : hbA;
      // wave K-slice: k = w*256 .. +255; A-frag row = R0g + rt*16 + fr
      size_t abase = ((size_t)(R0g + fr)) * 256 + (w << 6) + (kg << 1);
      bf16x8 a[2][8];
      #pragma unroll
      for (int rt = 0; rt < 2; ++rt){
        #pragma unroll
        for (int j = 0; j < 8; ++j){
          size_t o = abase + (size_t)rt * 4096 + j * 8;
          u64x2 uu;
          uu[0] = __hip_atomic_load(hin + o,     __ATOMIC_RELAXED, __HIP_MEMORY_SCOPE_AGENT);
          uu[1] = __hip_atomic_load(hin + o + 1, __ATOMIC_RELAXED, __HIP_MEMORY_SCOPE_AGENT);
          a[rt][j] = __builtin_bit_cast(bf16x8, uu);
        }
      }
      #pragma unroll
      for (int j = 0; j < 8; ++j){
        int ks = (w << 3) + j;
        bf16x8 b0 = *(const bf16x8*)(wbase + (size_t)(     ks) * 512);
        bf16x8 b1 = *(const bf16x8*)(wbase + (size_t)(32 + ks) * 512);
        bf16x8 b2 = *(const bf16x8*)(wbase + (size_t)(64 + ks) * 512);
        acc[0][0] = __builtin_amdgcn_mfma_f32_16x16x32_bf16(a[0][j], b0, acc[0][0], 0,0,0);
        acc[0][1] = __builtin_amdgcn_mfma_f32_16x16x32_bf16(a[0][j], b1, acc[0][1], 0,0,0);
        acc[0][2] = __builtin_amdgcn_mfma_f32_16x16x32_bf16(a[0][j], b2, acc[0][2], 0,0,0);
        acc[1][0] = __builtin_amdgcn_mfma_f32_16x16x32_bf16(a[1][j], b0, acc[1][0], 0,0,0);
        acc[1][1] = __builtin_amdgcn_mfma_f32_16x16x32_bf16(a[1][j], b1, acc[1][1], 0,0,0);
        acc[1][2] = __builtin_amdgcn_mfma_f32_16x16x32_bf16(a[1][j], b2, acc[1][2], 0,0,0);
      }
    }

    // partials -> LDS (padded)
    #pragma unroll
    for (int rt = 0; rt < 2; ++rt)
      #pragma unroll
      for (int g = 0; g < 3; ++g)
        #pragma unroll
        for (int qq = 0; qq < 4; ++qq)
          redF[(((w * 6 + rt * 3 + g) * 4 + qq) * 65) + lane] = acc[rt][g][qq];
    __syncthreads();   // reduction barrier

    // epilogue: sum 4 waves' partials for my (row, 2 cols)
    float v0[3], v1[3];
    #pragma unroll
    for (int g = 0; g < 3; ++g){
      int fo = ((rt_ * 3 + g) * 4 + q) * 65 + lbase;
      float s0 = 0.f, s1 = 0.f;
      #pragma unroll
      for (int ww = 0; ww < 4; ++ww){
        s0 += redF[ww * 1560 + fo];
        s1 += redF[ww * 1560 + fo + 1];
      }
      v0[g] = s0; v1[g] = s1;
    }

    float rA = sigm(grA + v0[0] + brA);
    float zA = sigm(gzA + v0[1] + bzA);
    float nA = tanh_(gnA + biA + rA * (v0[2] + bhA));
    float h0 = (1.0f - zA) * nA + zA * hprev0;
    float rB = sigm(grB + v1[0] + brB);
    float zB = sigm(gzB + v1[1] + bzB);
    float nB = tanh_(gnB + biB + rB * (v1[2] + bhB));
    float h1 = (1.0f - zB) * nB + zB * hprev1;
    hprev0 = h0; hprev1 = h1;

    // publish h (one u32 per thread) -> drained barrier -> tid0 flag store
    unsigned long long* hout = (t & 1) ? hbA : hbB;
    unsigned hu = (unsigned)f2bf(h0) | ((unsigned)f2bf(h1) << 16);
    __hip_atomic_store((unsigned*)hout + (((size_t)grow_ * HID + colA) >> 1), hu,
                       __ATOMIC_RELAXED, __HIP_MEMORY_SCOPE_AGENT);
    asm volatile("s_waitcnt vmcnt(0)" ::: "memory");
    __syncthreads();   // all waves' h-stores ack'd at LLC
    if (tid == 0 && s < TCH - 1)
      __hip_atomic_store(flags + (size_t)(s * 4 + rg) * 64 + ct, 1u,
                         __ATOMIC_RELAXED, __HIP_MEMORY_SCOPE_AGENT);

    // bulk outputs OFF the critical path
    if (ys_out){
      float2 yv = { h0, h1 };
      *(float2*)&ys_out[((size_t)t * BATCH + grow_) * HID + colA] = yv;
    }
    if (x_next)
      *(unsigned*)&x_next[((size_t)s * BATCH + grow_) * HID + colA] = hu;
    if (t == SEQ - 1){
      float2 sv = { h0, h1 };
      *(float2*)&state_out[(size_t)grow_ * HID + colA] = sv;
    }
    if (s == TCH - 1){ hfp[0] = hprev0; hfp[1] = hprev1; }

    // prefetch next step's gi
    if (s + 1 < TCH){
      const float* gA = giA + (size_t)(s + 1) * BATCH;
      const float* gB = giB + (size_t)(s + 1) * BATCH;
      grA = gA[0]; gzA = gA[GOFF]; gnA = gA[2*GOFF];
      grB = gB[0]; gzB = gB[GOFF]; gnB = gB[2*GOFF];
    }
  }
}

// ---------------- launch ----------------

extern "C" void kernel_launch(void* const* d_in, const int* in_sizes, int n_in,
                              void* d_out, int out_size, void* d_ws, size_t ws_size,
                              hipStream_t stream){
  (void)in_sizes; (void)n_in; (void)out_size; (void)ws_size;
  const int*   src  = (const int*)  d_in[0];
  const float* embW = (const float*)d_in[1];
  const float* Wih  = (const float*)d_in[2];
  const float* Whh  = (const float*)d_in[3];
  const float* bih  = (const float*)d_in[4];
  const float* bhh  = (const float*)d_in[5];
  float* out = (float*)d_out;

  char* ws = (char*)d_ws;
  size_t off = 0;
  auto carve = [&](size_t bytes) -> void* {
    void* p = ws + off;
    off += (bytes + 255) & ~(size_t)255;
    return p;
  };
  const size_t WELEM = (size_t)2 * H3 * HID;
  const int NFLAG = 2 * NCH * TCH * 4 * 64;      // u32 flags, all launches (512 KB)
  unsigned short* wihb = (unsigned short*)carve(WELEM * 2);
  unsigned short* whhb = (unsigned short*)carve(WELEM * 2);
  unsigned short* x0   = (unsigned short*)carve((size_t)SEQ*BATCH*HID*2);
  unsigned short* x1   = (unsigned short*)carve((size_t)SEQ*BATCH*HID*2);
  float*          gi   = (float*)         carve((size_t)CROWS*H3*4);
  unsigned long long* hbA = (unsigned long long*)carve((size_t)BATCH*HID*2);
  unsigned long long* hbB = (unsigned long long*)carve((size_t)BATCH*HID*2);
  float*          hf32 = (float*)         carve((size_t)256*256*2*4);
  unsigned*       flags= (unsigned*)      carve((size_t)NFLAG * 4);

  cvt_bf16<<<2048, 256, 0, stream>>>(Wih, wihb, (int)(WELEM/4));
  cvt_bf16<<<2048, 256, 0, stream>>>(Whh, whhb, (int)(WELEM/4));
  embed_gather<<<SEQ*BATCH, 256, 0, stream>>>(src, embW, x0);
  zero_u32<<<(NFLAG + 255)/256, 256, 0, stream>>>(flags, NFLAG);

  float* state = out + (size_t)SEQ*BATCH*HID;
  for (int l = 0; l < 2; ++l){
    const float* bihl = bih + l*H3;
    const float* bhhl = bhh + l*H3;
    const unsigned short* wl = wihb + (size_t)l*H3*HID;
    const unsigned short* vl = whhb + (size_t)l*H3*HID;
    for (int cch = 0; cch < NCH; ++cch){
      const unsigned short* Achunk = (l == 0) ? (x0 + (size_t)cch*CROWS*HID)
                                              : (x1 + (size_t)cch*CROWS*HID);
      gemm_xw<<<dim3(CROWS/BM, H3/BN), 256, 0, stream>>>(Achunk, wl, gi);
      int launch_id = l*NCH + cch;
      gru_persist<<<256, 256, 0, stream>>>(
          vl, bihl, bhhl, gi,
          (l == 1) ? out : nullptr,
          (l == 0) ? (x1 + (size_t)cch*CROWS*HID) : nullptr,
          hbA, hbB, hf32,
          state + (size_t)l*BATCH*HID,
          cch*TCH,
          flags + (size_t)launch_id * TCH * 4 * 64);
    }
  }
}